// Round 1
// baseline (1399.137 us; speedup 1.0000x reference)
//
#include <hip/hip_runtime.h>
#include <math.h>

#define Lr 32
#define Hh 128
#define NCELL (Lr * Lr)
#define NEPS 1e-8f
#define WCELL (33 * 256)   // h2 elements per cell in transposed weight buffer

typedef _Float16 f16;
typedef f16 h2 __attribute__((ext_vector_type(2)));

// Barrier with LDS flush only (in-flight global prefetches survive).
__device__ __forceinline__ void bar_lds() {
    asm volatile("s_waitcnt lgkmcnt(0)\n\ts_barrier" ::: "memory");
}

template<int CTRL>
__device__ __forceinline__ float dpp_get(float x) {
    return __int_as_float(__builtin_amdgcn_update_dpp(
        0, __float_as_int(x), CTRL, 0xf, 0xf, true));
}
// DPP ctrl: 0xB1 = quad_perm[1,0,3,2] (xor1), 0x4E = quad_perm[2,3,0,1] (xor2),
//           0x141 = row_half_mirror (^7), 0x140 = row_mirror (^15)

__device__ __forceinline__ float rlane(float x, int l) {
    return __int_as_float(__builtin_amdgcn_readlane(__float_as_int(x), l));
}

__device__ __forceinline__ float dot2(h2 a, h2 b, float c) {
    return __builtin_amdgcn_fdot2(a, b, c, false);   // v_dot2_f32_f16
}

// tanh via clamped exp: matches tanhf to ~1e-6, ~7 instrs instead of ~60.
__device__ __forceinline__ float fast_tanh(float x) {
    x = fminf(9.f, fmaxf(-9.f, x));
    const float e = __expf(2.f * x);
    return 1.f - 2.f / (e + 1.f);
}

__device__ __forceinline__ int cell_of(int s) {
    const int i = s >> 5, jj = s & 31;
    const int c = (i & 1) ? (Lr - 1 - jj) : jj;
    return i * Lr + c;
}

// W1[cell][k][m] (fp32, k<128, m<130) -> Wt[cell][q][t] (h2, q<33, t<256):
// slot q*256+t holds pair p=(t&1)*33+q of row k=t>>1:
//   (W[k][2p], W[k][2p+1]), zero for m>=130.  LOADW then reads 1KB/instr coalesced.
__global__ __launch_bounds__(256)
void transpose_w(const float* __restrict__ W1, h2* __restrict__ Wt) {
    __shared__ __align__(16) f16 tile[Hh * 132];
    const int cell = blockIdx.x;
    const float* src = W1 + (size_t)cell * (Hh * 130);
    for (int idx = threadIdx.x; idx < Hh * 130; idx += 256) {
        const int kk = idx / 130, m = idx - kk * 130;
        tile[kk * 132 + m] = (f16)src[idx];
    }
    for (int idx = threadIdx.x; idx < Hh * 2; idx += 256)
        tile[(idx >> 1) * 132 + 130 + (idx & 1)] = (f16)0.f;
    __syncthreads();
    h2* dst = Wt + (size_t)cell * WCELL;
    const h2* t2 = (const h2*)tile;
    for (int idx = threadIdx.x; idx < WCELL; idx += 256) {
        const int q = idx >> 8, tt = idx & 255;
        const int kk = tt >> 1, p = (tt & 1) * 33 + q;
        dst[idx] = t2[kk * 66 + p];
    }
}

// 256 blocks x 2 batch elements (1 block/CU; weights loaded once, dotted twice).
// 256 threads: lane pair (2k,2k+1) owns output k; half=t&1 is the m-split.
// One barrier per cell: pair-combine via DPP (no LDS partial round-trip),
// head reduce via DPP+readlane (no ds_bpermute chain), inp/fpart parity
// double-buffered in LDS. All inner state fp16; dots via v_dot2_f32_f16.
__global__ __launch_bounds__(256)
void rnn2d(const float* __restrict__ samples,
           const h2* __restrict__ Wt,
           const float* __restrict__ b1,
           const float* __restrict__ Wf,
           const float* __restrict__ bfv,
           float* __restrict__ out)
{
    // inp slot layout per [e][parity]: pairs 0..32 at slots 0..32 (half0),
    // pairs 33..65 at slots 36..68 (half1, 16B-aligned base); holes zero.
    __shared__ __align__(16) h2  inp[2][2][72];
    __shared__ __align__(16) f16 hvh[2][Lr * Hh];   // vertical hidden, fp16, 16KB
    __shared__ float smp2[2][NCELL];                // staged spins, 8KB
    __shared__ float bfs[NCELL];                    // head bias, 4KB
    __shared__ float fp_[2][2][4];                  // head partials [e][parity][wave]
    __shared__ float lpb[4];

    const int t    = threadIdx.x;
    const int k    = t >> 1;
    const int half = t & 1;
    const int w    = t >> 6;
    const int b0   = blockIdx.x * 2;

    {
        f16* z1 = (f16*)inp;
        for (int idx = t; idx < 2 * 2 * 72 * 2; idx += 256) z1[idx] = (f16)0.f;
        f16* z2 = (f16*)hvh;
        for (int idx = t; idx < 2 * Lr * Hh; idx += 256) z2[idx] = (f16)0.f;
        for (int idx = t; idx < NCELL; idx += 256) {
            smp2[0][idx] = samples[(size_t)b0 * NCELL + idx];
            smp2[1][idx] = samples[(size_t)(b0 + 1) * NCELL + idx];
            bfs[idx] = bfv[idx];
        }
        if (t == 0) {           // cell 0 input: xh=xv=0 -> pair0 = (0, 2)
            h2 x0; x0.x = (f16)0.f; x0.y = (f16)2.f;
            inp[0][0][0] = x0;
            inp[1][0][0] = x0;
        }
    }
    float lp = 0.f;
    __syncthreads();

    const h2* wbase = Wt + t;
    h2 wA[33], wB[33];
    float bvA, bvB, wvA, wvB;

#define LOADW(S, BUF, BV, WV)                                               \
    {                                                                       \
        const int cc_ = cell_of(S);                                         \
        const h2* p_ = wbase + (size_t)cc_ * WCELL;                         \
        _Pragma("unroll")                                                   \
        for (int q_ = 0; q_ < 33; ++q_) BUF[q_] = p_[q_ * 256];             \
        BV = 2.f * b1[cc_ * Hh + k];                                        \
        WV = Wf[cc_ * Hh + k];                                              \
    }

#define PROCESS(S, Q, BUF, BV, WV)                                          \
    {                                                                       \
        const int i_ = (S) >> 5, j_ = (S) & 31;                             \
        const int c_ = (i_ & 1) ? (Lr - 1 - j_) : j_;                       \
        const int sn_ = ((S) + 1 < NCELL) ? (S) + 1 : (S);                  \
        const int in_ = sn_ >> 5, jn_ = sn_ & 31;                           \
        const int cn_ = (in_ & 1) ? (Lr - 1 - jn_) : jn_;                   \
        /* prefetch vertical state for next cell's column (own k only) */   \
        const float hvn0 = (float)hvh[0][cn_ * Hh + k];                     \
        const float hvn1 = (float)hvh[1][cn_ * Hh + k];                     \
        /* deferred lp tail for cell S-1: one lane per wave, one log each */\
        if (((t & 63) == 4) && (S) > 0) {                                   \
            const int e_ = w >> 1, r_ = w & 1;                              \
            const int cp_ = cell_of((S) - 1);                               \
            const float z_ = fp_[e_][Q][0] + fp_[e_][Q][1]                  \
                           + fp_[e_][Q][2] + fp_[e_][Q][3] + bfs[cp_];      \
            const float xh_ = 1.f / (1.f + __expf(-z_));                    \
            const float m_ = smp2[e_][cp_];                                 \
            lp += (r_ == 0) ? __logf(xh_ + NEPS) * m_                       \
                            : __logf(1.f - xh_ + NEPS) * (1.f - m_);        \
        }                                                                   \
        /* half-dot from prefetched weight regs, both batch elements */     \
        const h2* ip0 = &inp[0][Q][half * 36];                              \
        const h2* ip1 = &inp[1][Q][half * 36];                              \
        float a00 = 0.f, a01 = 0.f, a10 = 0.f, a11 = 0.f;                   \
        _Pragma("unroll")                                                   \
        for (int q_ = 0; q_ < 33; ++q_) {                                   \
            if (q_ & 1) { a01 = dot2(BUF[q_], ip0[q_], a01);                \
                          a11 = dot2(BUF[q_], ip1[q_], a11); }              \
            else        { a00 = dot2(BUF[q_], ip0[q_], a00);               \
                          a10 = dot2(BUF[q_], ip1[q_], a10); }              \
        }                                                                   \
        float s0 = a00 + a01, s1 = a10 + a11;                               \
        s0 += dpp_get<0xB1>(s0);   /* pair combine: full 130-dot */         \
        s1 += dpp_get<0xB1>(s1);                                            \
        const float h0 = fast_tanh(s0 + (BV));                              \
        const float h1 = fast_tanh(s1 + (BV));                              \
        /* head: per-wave sum of h[k]*wf[k] (values pair-duplicated, so */  \
        /* skip xor1; butterfly xor2/4/8 then rows via readlane) */         \
        float f0 = h0 * (WV), f1 = h1 * (WV);                               \
        f0 += dpp_get<0x4E>(f0);  f1 += dpp_get<0x4E>(f1);                  \
        f0 += dpp_get<0x141>(f0); f1 += dpp_get<0x141>(f1);                 \
        f0 += dpp_get<0x140>(f0); f1 += dpp_get<0x140>(f1);                 \
        f0 = f0 + rlane(f0, 16) + rlane(f0, 32) + rlane(f0, 48);            \
        f1 = f1 + rlane(f1, 16) + rlane(f1, 32) + rlane(f1, 48);            \
        if ((S) + 1 < NCELL) {                                              \
            /* next-cell input value for own k: horizontal + vertical */    \
            const float v0 = ((jn_ == 0) ? 0.f : h0)                        \
                           + ((cn_ == c_) ? h0 : hvn0);                     \
            const float v1 = ((jn_ == 0) ? 0.f : h1)                        \
                           + ((cn_ == c_) ? h1 : hvn1);                     \
            const float v0p = dpp_get<0x4E>(v0);  /* partner k's value */   \
            const float v1p = dpp_get<0x4E>(v1);                            \
            if ((t & 3) == 0) {                                             \
                const int p_ = (t >> 2) + 1;                                \
                const int sl_ = (p_ < 33) ? p_ : p_ + 3;                    \
                h2 u0; u0.x = (f16)v0; u0.y = (f16)v0p;                     \
                h2 u1; u1.x = (f16)v1; u1.y = (f16)v1p;                     \
                inp[0][(Q) ^ 1][sl_] = u0;                                  \
                inp[1][(Q) ^ 1][sl_] = u1;                                  \
            }                                                               \
            if (t == 0) {                                                   \
                const float xh0 = (jn_ == 0) ? 0.f : smp2[0][i_ * Lr + c_]; \
                const float xv0 = (in_ == 0) ? 0.f                          \
                                             : smp2[0][(in_ - 1) * Lr + cn_]; \
                const float xh1 = (jn_ == 0) ? 0.f : smp2[1][i_ * Lr + c_]; \
                const float xv1 = (in_ == 0) ? 0.f                          \
                                             : smp2[1][(in_ - 1) * Lr + cn_]; \
                h2 x0; x0.x = (f16)(xh0 + xv0); x0.y = (f16)(2.f - xh0 - xv0); \
                h2 x1; x1.x = (f16)(xh1 + xv1); x1.y = (f16)(2.f - xh1 - xv1); \
                inp[0][(Q) ^ 1][0] = x0;                                    \
                inp[1][(Q) ^ 1][0] = x1;                                    \
            }                                                               \
        }                                                                   \
        hvh[0][c_ * Hh + k] = (f16)h0;  /* k-partitioned: race-free */      \
        hvh[1][c_ * Hh + k] = (f16)h1;                                      \
        if ((t & 63) == 0) {                                                \
            fp_[0][(Q) ^ 1][w] = f0;                                        \
            fp_[1][(Q) ^ 1][w] = f1;                                        \
        }                                                                   \
        bar_lds();   /* the single barrier per cell */                      \
    }

    LOADW(0, wA, bvA, wvA);
    for (int s = 0; s < NCELL; s += 2) {
        LOADW(s + 1, wB, bvB, wvB);
        PROCESS(s, 0, wA, bvA, wvA);
        if (s + 2 < NCELL) LOADW(s + 2, wA, bvA, wvA);
        PROCESS(s + 1, 1, wB, bvB, wvB);
    }
#undef LOADW
#undef PROCESS

    // tail: lp for cell 1023 (fpart parity 0, flushed by the final barrier)
    if ((t & 63) == 4) {
        const int e_ = w >> 1, r_ = w & 1;
        const int cp_ = cell_of(NCELL - 1);
        const float z_ = fp_[e_][0][0] + fp_[e_][0][1]
                       + fp_[e_][0][2] + fp_[e_][0][3] + bfs[cp_];
        const float xh_ = 1.f / (1.f + __expf(-z_));
        const float m_ = smp2[e_][cp_];
        lp += (r_ == 0) ? __logf(xh_ + NEPS) * m_
                        : __logf(1.f - xh_ + NEPS) * (1.f - m_);
        lpb[w] = lp;
    }
    __syncthreads();
    if (t == 0) {
        out[b0]     = lpb[0] + lpb[1];
        out[b0 + 1] = lpb[2] + lpb[3];
    }
}

extern "C" void kernel_launch(void* const* d_in, const int* in_sizes, int n_in,
                              void* d_out, int out_size, void* d_ws, size_t ws_size,
                              hipStream_t stream) {
    const float* samples = (const float*)d_in[0];
    const float* W1      = (const float*)d_in[1];
    const float* b1      = (const float*)d_in[2];
    const float* Wf      = (const float*)d_in[3];
    const float* bf      = (const float*)d_in[4];
    float* outp = (float*)d_out;
    h2* Wt = (h2*)d_ws;   // 1024 * 8448 * 4B = 34.6 MB (same footprint as before)

    transpose_w<<<1024, 256, 0, stream>>>(W1, Wt);
    rnn2d<<<256, 256, 0, stream>>>(samples, Wt, b1, Wf, bf, outp);
}